// Round 15
// baseline (6514.232 us; speedup 1.0000x reference)
//
#include <hip/hip_runtime.h>
#include <math.h>

#define NWG 256
#define NTH 512

typedef float vf2 __attribute__((ext_vector_type(2)));

// agent-coherent (L2-bypassing) access — cross-XCD exchange primitives
__device__ __forceinline__ float cload(const float* p) {
    return __hip_atomic_load(p, __ATOMIC_RELAXED, __HIP_MEMORY_SCOPE_AGENT);
}
__device__ __forceinline__ void cstore(float* p, float v) {
    __hip_atomic_store(p, v, __ATOMIC_RELAXED, __HIP_MEMORY_SCOPE_AGENT);
}
__device__ __forceinline__ vf2 cload2(const float* p) {
    unsigned long long u = __hip_atomic_load((const unsigned long long*)p,
                                             __ATOMIC_RELAXED, __HIP_MEMORY_SCOPE_AGENT);
    vf2 r;
    r.x = __uint_as_float((unsigned)u);
    r.y = __uint_as_float((unsigned)(u >> 32));
    return r;
}
__device__ __forceinline__ void cstore2(float* p, vf2 v) {
    unsigned long long u = ((unsigned long long)__float_as_uint(v.y) << 32)
                         | (unsigned long long)__float_as_uint(v.x);
    __hip_atomic_store((unsigned long long*)p, u,
                       __ATOMIC_RELAXED, __HIP_MEMORY_SCOPE_AGENT);
}

// two-level arrive (16 groups x 16 WGs); gen monotonic, counters never reset
__device__ __forceinline__ void bar_arrive(unsigned* tree, int w, unsigned gen) {
    unsigned p = __hip_atomic_fetch_add(&tree[(w >> 4) * 16], 1u,
                                        __ATOMIC_RELAXED, __HIP_MEMORY_SCOPE_AGENT);
    if (p + 1u == 16u * gen) {
        unsigned q = __hip_atomic_fetch_add(&tree[272], 1u,
                                            __ATOMIC_RELAXED, __HIP_MEMORY_SCOPE_AGENT);
        if (q + 1u == 16u * gen)
            __hip_atomic_store(&tree[288], gen,
                               __ATOMIC_RELAXED, __HIP_MEMORY_SCOPE_AGENT);
    }
}
__device__ __forceinline__ void bar_wait(unsigned* tree, unsigned gen) {
    unsigned f;
    do {
        f = __hip_atomic_load(&tree[288], __ATOMIC_RELAXED, __HIP_MEMORY_SCOPE_AGENT);
        if (f < gen) __builtin_amdgcn_s_sleep(2);
    } while (f < gen);
}

// init: initial h states -> pair-layout parity-1 buffers; zero barriers
__global__ void k_init(const float* __restrict__ h0in, float* __restrict__ h0buf,
                       float* __restrict__ h1buf, unsigned* __restrict__ bar) {
    int i = blockIdx.x * 256 + threadIdx.x;
    if (i < 32768) {
        int m = i >> 9, k = i & 511;
        h0buf[32768 + ((k >> 1) << 7) + (m << 1) + (k & 1)] = h0in[i];
    } else if (i < 65536) {
        int j = i - 32768;
        int m = j >> 9, k = j & 511;
        h1buf[32768 + ((k >> 1) << 7) + (m << 1) + (k & 1)] = h0in[i];
    } else if (i < 66560) {
        bar[i - 65536] = 0u;
    }
}

// transpose x [64][512][16] -> xT [512][64][16]
__global__ void k_xt(const float* __restrict__ x, float* __restrict__ xT) {
    int i = blockIdx.x * 256 + threadIdx.x;
    if (i < 131072) {
        int mt = i >> 2, q = i & 3;
        int m = mt >> 9, t = mt & 511;
        float4 v = *(const float4*)(x + (size_t)i * 4);
        *(float4*)(xT + ((size_t)t * 64 + m) * 16 + q * 4) = v;
    }
}

// Persistent cooperative kernel (512 thr, 8 waves, k-split 64/wave).
// R15 = R13 (split barriers, scalar-path weights, packed pairs) +
//   (a) manual 2-chunk software pipeline in both phases: load chunk kb+1
//       while computing kb -> hides ~3 of 4 LLC-latency exposures/phase.
//   (b) phase-3 chunk-0/1 loads issued BEFORE biophys so WG0's biophys
//       latency overlaps them (it was serial on the global critical path).
// NOTE: 1 WG/CU cooperative => VGPR count does not affect occupancy; the
// pipeline's larger live set is free (R14's regression was its barrier).
__global__ __launch_bounds__(NTH, 2)
void k_fused(const float* __restrict__ xT,
             const float* __restrict__ Wih0, const float* __restrict__ Whh0,
             const float* __restrict__ bih0, const float* __restrict__ bhh0,
             const float* __restrict__ Wih1, const float* __restrict__ Whh1,
             const float* __restrict__ bih1, const float* __restrict__ bhh1,
             const float* __restrict__ fcW, const float* __restrict__ fcb,
             const float* __restrict__ th0, const float* __restrict__ om0,
             float* __restrict__ out,
             float* __restrict__ h0buf, float* __restrict__ h1buf,
             float* __restrict__ apre_g, unsigned* __restrict__ bar)
{
    const int w = blockIdx.x, tid = threadIdx.x;
    const int v = tid >> 6, m = tid & 63;
    const int c0 = w * 2;
    // wave-uniform k-slice base: forces scalar weight fetches
    const int vu = __builtin_amdgcn_readfirstlane(v);
    const int ksu = vu * 64;
    unsigned* treeA = bar;          // h0 barrier
    unsigned* treeB = bar + 320;    // h1 barrier
    __shared__ float pl[8 * 12 * 64];
    __shared__ float pl2[8 * 64];

    // uniform row base pointers (local gate g = gt*2 + j, j = column)
    const float* wp0[6]; const float* wpi[6]; const float* wp1[6];
    #pragma unroll
    for (int g = 0; g < 6; ++g) {
        int row = (g >> 1) * 512 + c0 + (g & 1);
        wp0[g] = Whh0 + (size_t)row * 512 + ksu;
        wpi[g] = Wih1 + (size_t)row * 512 + ksu;
        wp1[g] = Whh1 + (size_t)row * 512 + ksu;
    }
    const bool isFC = (w >= 8 && w < 24);
    const float* fcp = fcW + (size_t)(isFC ? (w - 8) : 0) * 512 + ksu;

    // v0 holds biases for BOTH columns as float2
    vf2 br0 = {0,0}, bz0 = {0,0}, bin0 = {0,0}, bhn0 = {0,0};
    vf2 bi1r = {0,0}, bi1z = {0,0}, bi1n = {0,0};
    vf2 bh1r = {0,0}, bh1z = {0,0}, bh1n = {0,0};
    if (v == 0) {
        #pragma unroll
        for (int j = 0; j < 2; ++j) {
            int c = c0 + j;
            br0[j]  = bih0[c] + bhh0[c];
            bz0[j]  = bih0[512 + c] + bhh0[512 + c];
            bin0[j] = bih0[1024 + c]; bhn0[j] = bhh0[1024 + c];
            bi1r[j] = bih1[c]; bi1z[j] = bih1[512 + c]; bi1n[j] = bih1[1024 + c];
            bh1r[j] = bhh1[c]; bh1z[j] = bhh1[512 + c]; bh1n[j] = bhh1[1024 + c];
        }
    }
    // biophys state: WG 0, thread = chain*8 + joint
    float th = 0.f, om = 0.f, fb0 = 0.f, fb1 = 0.f;
    if (w == 0) {
        th = th0[tid]; om = om0[tid];
        fb0 = fcb[2 * (tid & 7)]; fb1 = fcb[2 * (tid & 7) + 1];
    }
    vf2 gi_r = {0,0}, gi_z = {0,0}, gi_n = {0,0};
    __syncthreads();

    for (int s = 0; s < 515; ++s) {
        const int pw0 = s & 1, pr0 = (s + 1) & 1;
        // ---- wait-h0(s): h0(s-1) pairs visible (arrived mid-step s-1) ----
        if (s >= 1) {
            if (tid == 0) bar_wait(treeA, (unsigned)s);
            __syncthreads();
        }
        // ---- fused phase 1+2: Whh0 & Wih1 dots over h0(s-1), pipelined ----
        if (s <= 512) {
            const float* hp = h0buf + pr0 * 32768 + (ksu >> 1) * 128 + m * 2;
            vf2 ca[8], cb[8];
            #pragma unroll
            for (int i = 0; i < 8; ++i) ca[i] = cload2(hp + i * 128);        // kb0
            #pragma unroll
            for (int i = 0; i < 8; ++i) cb[i] = cload2(hp + (8 + i) * 128);  // kb1
            vf2 a01[12];
            #pragma unroll
            for (int g = 0; g < 12; ++g) a01[g] = (vf2){0.f, 0.f};
            // compute kb0
            #pragma unroll
            for (int i = 0; i < 8; ++i) {
                vf2 hv = ca[i]; int ko = i * 2;
                #pragma unroll
                for (int g = 0; g < 6; ++g) {
                    a01[g]     += (*(const vf2*)(wp0[g] + ko)) * hv;
                    a01[6 + g] += (*(const vf2*)(wpi[g] + ko)) * hv;
                }
            }
            #pragma unroll
            for (int i = 0; i < 8; ++i) ca[i] = cload2(hp + (16 + i) * 128); // kb2
            // compute kb1
            #pragma unroll
            for (int i = 0; i < 8; ++i) {
                vf2 hv = cb[i]; int ko = 16 + i * 2;
                #pragma unroll
                for (int g = 0; g < 6; ++g) {
                    a01[g]     += (*(const vf2*)(wp0[g] + ko)) * hv;
                    a01[6 + g] += (*(const vf2*)(wpi[g] + ko)) * hv;
                }
            }
            #pragma unroll
            for (int i = 0; i < 8; ++i) cb[i] = cload2(hp + (24 + i) * 128); // kb3
            // compute kb2
            #pragma unroll
            for (int i = 0; i < 8; ++i) {
                vf2 hv = ca[i]; int ko = 32 + i * 2;
                #pragma unroll
                for (int g = 0; g < 6; ++g) {
                    a01[g]     += (*(const vf2*)(wp0[g] + ko)) * hv;
                    a01[6 + g] += (*(const vf2*)(wpi[g] + ko)) * hv;
                }
            }
            // compute kb3
            #pragma unroll
            for (int i = 0; i < 8; ++i) {
                vf2 hv = cb[i]; int ko = 48 + i * 2;
                #pragma unroll
                for (int g = 0; g < 6; ++g) {
                    a01[g]     += (*(const vf2*)(wp0[g] + ko)) * hv;
                    a01[6 + g] += (*(const vf2*)(wpi[g] + ko)) * hv;
                }
            }
            #pragma unroll
            for (int g = 0; g < 12; ++g) pl[(v * 12 + g) * 64 + m] = a01[g].x + a01[g].y;
        }
        __syncthreads();
        // ---- combine A (v0, both columns): h0(s) paired update + gi1 regs ----
        if (v == 0) {
            if (s <= 511) {
                vf2 hr = {0,0}, hz = {0,0}, hn = {0,0};
                #pragma unroll
                for (int u = 0; u < 8; ++u) {
                    hr.x += pl[(u * 12 + 0) * 64 + m]; hr.y += pl[(u * 12 + 1) * 64 + m];
                    hz.x += pl[(u * 12 + 2) * 64 + m]; hz.y += pl[(u * 12 + 3) * 64 + m];
                    hn.x += pl[(u * 12 + 4) * 64 + m]; hn.y += pl[(u * 12 + 5) * 64 + m];
                }
                const float* xp = xT + ((size_t)s * 64 + m) * 16;
                vf2 ir = {0,0}, iz = {0,0}, in_ = {0,0};
                #pragma unroll
                for (int k = 0; k < 16; ++k) {
                    float xv = xp[k];
                    ir.x  += Wih0[(size_t)(c0) * 16 + k] * xv;
                    ir.y  += Wih0[(size_t)(c0 + 1) * 16 + k] * xv;
                    iz.x  += Wih0[(size_t)(512 + c0) * 16 + k] * xv;
                    iz.y  += Wih0[(size_t)(512 + c0 + 1) * 16 + k] * xv;
                    in_.x += Wih0[(size_t)(1024 + c0) * 16 + k] * xv;
                    in_.y += Wih0[(size_t)(1024 + c0 + 1) * 16 + k] * xv;
                }
                vf2 hold = cload2(&h0buf[pr0 * 32768 + w * 128 + m * 2]);
                vf2 hnew;
                #pragma unroll
                for (int j = 0; j < 2; ++j) {
                    float r = 1.f / (1.f + expf(-(ir[j] + hr[j] + br0[j])));
                    float z = 1.f / (1.f + expf(-(iz[j] + hz[j] + bz0[j])));
                    float n = tanhf(in_[j] + bin0[j] + r * (hn[j] + bhn0[j]));
                    hnew[j] = (1.f - z) * n + z * hold[j];
                }
                cstore2(&h0buf[pw0 * 32768 + w * 128 + m * 2], hnew);
            }
            if (s >= 1 && s <= 512) {
                gi_r = bi1r; gi_z = bi1z; gi_n = bi1n;
                #pragma unroll
                for (int u = 0; u < 8; ++u) {
                    gi_r.x += pl[(u * 12 + 6) * 64 + m];  gi_r.y += pl[(u * 12 + 7) * 64 + m];
                    gi_z.x += pl[(u * 12 + 8) * 64 + m];  gi_z.y += pl[(u * 12 + 9) * 64 + m];
                    gi_n.x += pl[(u * 12 + 10) * 64 + m]; gi_n.y += pl[(u * 12 + 11) * 64 + m];
                }
            }
        }
        // ---- arrive-h0(s+1) + wait-h1(s) ----
        __syncthreads();                 // drains h0 cstores for all waves
        if (tid == 0) {
            bar_arrive(treeA, w, (unsigned)(s + 1));
            bar_wait(treeB, (unsigned)s);
        }
        __syncthreads();
        // ---- phase 3 chunk-0/1 loads first; biophys under their shadow ----
        const bool p3 = (s >= 1 && s <= 513);
        vf2 ca[8], cb[8];
        const float* hp1 = h1buf + (s & 1) * 32768 + (ksu >> 1) * 128 + m * 2;
        if (p3) {
            #pragma unroll
            for (int i = 0; i < 8; ++i) ca[i] = cload2(hp1 + i * 128);        // kb0
            #pragma unroll
            for (int i = 0; i < 8; ++i) cb[i] = cload2(hp1 + (8 + i) * 128);  // kb1
        }
        // ---- biophys (WG0): consume apre(s-1) -> theta(s-3) ----
        if (w == 0 && s >= 3) {
            int mc = tid >> 3, j = tid & 7;
            const float* ap = apre_g + ((s + 1) & 1) * 1024;
            float a0 = 1.f / (1.f + expf(-(cload(&ap[(2 * j) * 64 + mc]) + fb0)));
            float a1 = 1.f / (1.f + expf(-(cload(&ap[(2 * j + 1) * 64 + mc]) + fb1)));
            float F0 = (100.f + 2000.f * a0) * (0.06f + 0.006f * a0 + 0.05f * th);
            float F1 = (100.f + 2000.f * a1) * (0.06f + 0.006f * a1 - 0.05f * th);
            float tau = 0.05f * (F1 - F0);
            float acc = (tau - 5.f * th - 0.3f * om) * 250.f;
            om += (1.f / 60.f) * acc;
            th += (1.f / 60.f) * om;
            out[((size_t)mc * 512 + (s - 3)) * 8 + j] = th;
        }
        // ---- phase 3: Whh1 + FC dots over h1(s-1), pipelined ----
        if (p3) {
            vf2 a2[6];
            #pragma unroll
            for (int g = 0; g < 6; ++g) a2[g] = (vf2){0.f, 0.f};
            vf2 fd = {0.f, 0.f};
            // compute kb0
            #pragma unroll
            for (int i = 0; i < 8; ++i) {
                vf2 hv = ca[i]; int ko = i * 2;
                #pragma unroll
                for (int g = 0; g < 6; ++g) a2[g] += (*(const vf2*)(wp1[g] + ko)) * hv;
                fd += (*(const vf2*)(fcp + ko)) * hv;
            }
            #pragma unroll
            for (int i = 0; i < 8; ++i) ca[i] = cload2(hp1 + (16 + i) * 128); // kb2
            // compute kb1
            #pragma unroll
            for (int i = 0; i < 8; ++i) {
                vf2 hv = cb[i]; int ko = 16 + i * 2;
                #pragma unroll
                for (int g = 0; g < 6; ++g) a2[g] += (*(const vf2*)(wp1[g] + ko)) * hv;
                fd += (*(const vf2*)(fcp + ko)) * hv;
            }
            #pragma unroll
            for (int i = 0; i < 8; ++i) cb[i] = cload2(hp1 + (24 + i) * 128); // kb3
            // compute kb2
            #pragma unroll
            for (int i = 0; i < 8; ++i) {
                vf2 hv = ca[i]; int ko = 32 + i * 2;
                #pragma unroll
                for (int g = 0; g < 6; ++g) a2[g] += (*(const vf2*)(wp1[g] + ko)) * hv;
                fd += (*(const vf2*)(fcp + ko)) * hv;
            }
            // compute kb3
            #pragma unroll
            for (int i = 0; i < 8; ++i) {
                vf2 hv = cb[i]; int ko = 48 + i * 2;
                #pragma unroll
                for (int g = 0; g < 6; ++g) a2[g] += (*(const vf2*)(wp1[g] + ko)) * hv;
                fd += (*(const vf2*)(fcp + ko)) * hv;
            }
            if (s <= 512) {
                #pragma unroll
                for (int g = 0; g < 6; ++g) pl[(v * 12 + g) * 64 + m] = a2[g].x + a2[g].y;
            }
            if (isFC && s >= 2) pl2[v * 64 + m] = fd.x + fd.y;
        }
        __syncthreads();
        // ---- combine B (v0, both columns): h1(s) paired update ----
        if (s >= 1 && s <= 512 && v == 0) {
            vf2 hr = {0,0}, hz = {0,0}, hn = {0,0};
            #pragma unroll
            for (int u = 0; u < 8; ++u) {
                hr.x += pl[(u * 12 + 0) * 64 + m]; hr.y += pl[(u * 12 + 1) * 64 + m];
                hz.x += pl[(u * 12 + 2) * 64 + m]; hz.y += pl[(u * 12 + 3) * 64 + m];
                hn.x += pl[(u * 12 + 4) * 64 + m]; hn.y += pl[(u * 12 + 5) * 64 + m];
            }
            vf2 hold = cload2(&h1buf[(s & 1) * 32768 + w * 128 + m * 2]);
            vf2 hnew;
            #pragma unroll
            for (int j = 0; j < 2; ++j) {
                float r = 1.f / (1.f + expf(-(gi_r[j] + hr[j] + bh1r[j])));
                float z = 1.f / (1.f + expf(-(gi_z[j] + hz[j] + bh1z[j])));
                float n = tanhf(gi_n[j] + r * (hn[j] + bh1n[j]));
                hnew[j] = (1.f - z) * n + z * hold[j];
            }
            cstore2(&h1buf[((s + 1) & 1) * 32768 + w * 128 + m * 2], hnew);
        }
        if (isFC && s >= 2 && s <= 513 && v == 2) {
            float p = 0.f;
            #pragma unroll
            for (int u = 0; u < 8; ++u) p += pl2[u * 64 + m];
            cstore(&apre_g[(s & 1) * 1024 + (w - 8) * 64 + m], p);
        }
        if (s == 514) break;
        // ---- arrive-h1(s+1): end of step ----
        __syncthreads();                 // drains h1/apre cstores
        if (tid == 0) bar_arrive(treeB, w, (unsigned)(s + 1));
    }
}

// ---------------------------------------------------------------------------
extern "C" void kernel_launch(void* const* d_in, const int* in_sizes, int n_in,
                              void* d_out, int out_size, void* d_ws, size_t ws_size,
                              hipStream_t stream) {
    const float* x     = (const float*)d_in[0];
    const float* W_ih0 = (const float*)d_in[1];
    const float* W_hh0 = (const float*)d_in[2];
    const float* b_ih0 = (const float*)d_in[3];
    const float* b_hh0 = (const float*)d_in[4];
    const float* W_ih1 = (const float*)d_in[5];
    const float* W_hh1 = (const float*)d_in[6];
    const float* b_ih1 = (const float*)d_in[7];
    const float* b_hh1 = (const float*)d_in[8];
    const float* fc_W  = (const float*)d_in[9];
    const float* fc_b  = (const float*)d_in[10];
    const float* h0    = (const float*)d_in[11];
    const float* th0   = (const float*)d_in[12];
    const float* om0   = (const float*)d_in[13];
    float* out = (float*)d_out;

    float* ws = (float*)d_ws;
    float* h0buf  = ws;                 // 2 x [256 pairs][64 chains][2] parity buffers
    float* h1buf  = h0buf + 65536;
    float* apre_g = h1buf + 65536;      // 2 x [16][64]
    unsigned* bar = (unsigned*)(apre_g + 2048);    // 1024 uints (two trees)
    float* xT     = (float*)(bar + 1024);          // [512][64][16]

    k_init<<<260, 256, 0, stream>>>(h0, h0buf, h1buf, bar);
    k_xt<<<512, 256, 0, stream>>>(x, xT);

    void* args[] = {(void*)&xT, (void*)&W_ih0, (void*)&W_hh0, (void*)&b_ih0,
                    (void*)&b_hh0, (void*)&W_ih1, (void*)&W_hh1, (void*)&b_ih1,
                    (void*)&b_hh1, (void*)&fc_W, (void*)&fc_b,
                    (void*)&th0, (void*)&om0, (void*)&out, (void*)&h0buf,
                    (void*)&h1buf, (void*)&apre_g, (void*)&bar};
    (void)hipLaunchCooperativeKernel((void*)k_fused, dim3(NWG), dim3(NTH),
                                     args, 0, stream);
}

// Round 16
// 4594.210 us; speedup vs baseline: 1.4179x; 1.4179x over previous
//
#include <hip/hip_runtime.h>
#include <math.h>

#define NWG 256
#define NTH 512

typedef float vf2 __attribute__((ext_vector_type(2)));

// agent-coherent (L2-bypassing) access — cross-XCD exchange primitives
__device__ __forceinline__ float cload(const float* p) {
    return __hip_atomic_load(p, __ATOMIC_RELAXED, __HIP_MEMORY_SCOPE_AGENT);
}
__device__ __forceinline__ void cstore(float* p, float v) {
    __hip_atomic_store(p, v, __ATOMIC_RELAXED, __HIP_MEMORY_SCOPE_AGENT);
}
__device__ __forceinline__ vf2 cload2(const float* p) {
    unsigned long long u = __hip_atomic_load((const unsigned long long*)p,
                                             __ATOMIC_RELAXED, __HIP_MEMORY_SCOPE_AGENT);
    vf2 r;
    r.x = __uint_as_float((unsigned)u);
    r.y = __uint_as_float((unsigned)(u >> 32));
    return r;
}
__device__ __forceinline__ void cstore2(float* p, vf2 v) {
    unsigned long long u = ((unsigned long long)__float_as_uint(v.y) << 32)
                         | (unsigned long long)__float_as_uint(v.x);
    __hip_atomic_store((unsigned long long*)p, u,
                       __ATOMIC_RELAXED, __HIP_MEMORY_SCOPE_AGENT);
}

// FLAG-ARRAY barrier: arrive = one relaxed store (no RMW round-trip on the
// critical path); wait = one wave scans all 256 flags (2x8B loads/lane) with
// __all. Latency last-arrival -> release ~1 LLC RT vs ~3 chained RTs for the
// counter tree (R13). Flags monotonic, never reset.
__device__ __forceinline__ void barf_arrive(unsigned* flags, int w, unsigned gen) {
    __hip_atomic_store(&flags[w], gen, __ATOMIC_RELAXED, __HIP_MEMORY_SCOPE_AGENT);
}
__device__ __forceinline__ void barf_wait(const unsigned* flags, int lane, unsigned gen) {
    const unsigned long long* p = (const unsigned long long*)(flags + lane * 4);
    for (;;) {
        unsigned long long a = __hip_atomic_load(p, __ATOMIC_RELAXED,
                                                 __HIP_MEMORY_SCOPE_AGENT);
        unsigned long long b = __hip_atomic_load(p + 1, __ATOMIC_RELAXED,
                                                 __HIP_MEMORY_SCOPE_AGENT);
        unsigned f0 = (unsigned)a, f1 = (unsigned)(a >> 32);
        unsigned f2 = (unsigned)b, f3 = (unsigned)(b >> 32);
        bool ok = (f0 >= gen) && (f1 >= gen) && (f2 >= gen) && (f3 >= gen);
        if (__all((int)ok)) return;
        __builtin_amdgcn_s_sleep(2);
    }
}

// init: initial h states -> pair-layout parity-1 buffers; zero flags
__global__ void k_init(const float* __restrict__ h0in, float* __restrict__ h0buf,
                       float* __restrict__ h1buf, unsigned* __restrict__ bar) {
    int i = blockIdx.x * 256 + threadIdx.x;
    if (i < 32768) {
        int m = i >> 9, k = i & 511;
        h0buf[32768 + ((k >> 1) << 7) + (m << 1) + (k & 1)] = h0in[i];
    } else if (i < 65536) {
        int j = i - 32768;
        int m = j >> 9, k = j & 511;
        h1buf[32768 + ((k >> 1) << 7) + (m << 1) + (k & 1)] = h0in[i];
    } else if (i < 66560) {
        bar[i - 65536] = 0u;
    }
}

// transpose x [64][512][16] -> xT [512][64][16]
__global__ void k_xt(const float* __restrict__ x, float* __restrict__ xT) {
    int i = blockIdx.x * 256 + threadIdx.x;
    if (i < 131072) {
        int mt = i >> 2, q = i & 3;
        int m = mt >> 9, t = mt & 511;
        float4 v = *(const float4*)(x + (size_t)i * 4);
        *(float4*)(xT + ((size_t)t * 64 + m) * 16 + q * 4) = v;
    }
}

// Persistent cooperative kernel (512 thr, 8 waves, k-split 64/wave).
// R16 = R13 compute structure (best known: scalar-path weights, packed
// pairs, unroll-1 chunks, split barriers) with the counter-tree barrier
// replaced by the flag-array barrier; arrive-A overlaps wait-B mid-step.
__global__ __launch_bounds__(NTH, 2)
void k_fused(const float* __restrict__ xT,
             const float* __restrict__ Wih0, const float* __restrict__ Whh0,
             const float* __restrict__ bih0, const float* __restrict__ bhh0,
             const float* __restrict__ Wih1, const float* __restrict__ Whh1,
             const float* __restrict__ bih1, const float* __restrict__ bhh1,
             const float* __restrict__ fcW, const float* __restrict__ fcb,
             const float* __restrict__ th0, const float* __restrict__ om0,
             float* __restrict__ out,
             float* __restrict__ h0buf, float* __restrict__ h1buf,
             float* __restrict__ apre_g, unsigned* __restrict__ bar)
{
    const int w = blockIdx.x, tid = threadIdx.x;
    const int v = tid >> 6, m = tid & 63;
    const int c0 = w * 2;
    // wave-uniform k-slice base: forces scalar weight fetches
    const int vu = __builtin_amdgcn_readfirstlane(v);
    const int ksu = vu * 64;
    unsigned* flagsA = bar;          // 256 dwords
    unsigned* flagsB = bar + 256;    // 256 dwords
    __shared__ float pl[8 * 12 * 64];
    __shared__ float pl2[8 * 64];

    // uniform row base pointers (local gate g = gt*2 + j, j = column)
    const float* wp0[6]; const float* wpi[6]; const float* wp1[6];
    #pragma unroll
    for (int g = 0; g < 6; ++g) {
        int row = (g >> 1) * 512 + c0 + (g & 1);
        wp0[g] = Whh0 + (size_t)row * 512 + ksu;
        wpi[g] = Wih1 + (size_t)row * 512 + ksu;
        wp1[g] = Whh1 + (size_t)row * 512 + ksu;
    }
    const bool isFC = (w >= 8 && w < 24);
    const float* fcp = fcW + (size_t)(isFC ? (w - 8) : 0) * 512 + ksu;

    // v0 holds biases for BOTH columns as float2
    vf2 br0 = {0,0}, bz0 = {0,0}, bin0 = {0,0}, bhn0 = {0,0};
    vf2 bi1r = {0,0}, bi1z = {0,0}, bi1n = {0,0};
    vf2 bh1r = {0,0}, bh1z = {0,0}, bh1n = {0,0};
    if (v == 0) {
        #pragma unroll
        for (int j = 0; j < 2; ++j) {
            int c = c0 + j;
            br0[j]  = bih0[c] + bhh0[c];
            bz0[j]  = bih0[512 + c] + bhh0[512 + c];
            bin0[j] = bih0[1024 + c]; bhn0[j] = bhh0[1024 + c];
            bi1r[j] = bih1[c]; bi1z[j] = bih1[512 + c]; bi1n[j] = bih1[1024 + c];
            bh1r[j] = bhh1[c]; bh1z[j] = bhh1[512 + c]; bh1n[j] = bhh1[1024 + c];
        }
    }
    // biophys state: WG 0, thread = chain*8 + joint
    float th = 0.f, om = 0.f, fb0 = 0.f, fb1 = 0.f;
    if (w == 0) {
        th = th0[tid]; om = om0[tid];
        fb0 = fcb[2 * (tid & 7)]; fb1 = fcb[2 * (tid & 7) + 1];
    }
    vf2 gi_r = {0,0}, gi_z = {0,0}, gi_n = {0,0};
    __syncthreads();

    for (int s = 0; s < 515; ++s) {
        const int pw0 = s & 1, pr0 = (s + 1) & 1;
        // ---- wait-h0(s): h0(s-1) pairs visible (arrived mid-step s-1) ----
        if (s >= 1) {
            if (v == 0) barf_wait(flagsA, m, (unsigned)s);
            __syncthreads();
        }
        // ---- fused phase 1+2: Whh0 & Wih1 dots over h0(s-1) ----
        if (s <= 512) {
            vf2 a01[12];
            #pragma unroll
            for (int g = 0; g < 12; ++g) a01[g] = (vf2){0.f, 0.f};
            #pragma unroll 1
            for (int kb = 0; kb < 4; ++kb) {
                vf2 hb[8];
                const float* hp = h0buf + pr0 * 32768 + (ksu / 2 + kb * 8) * 128 + m * 2;
                #pragma unroll
                for (int i = 0; i < 8; ++i) hb[i] = cload2(hp + i * 128);
                #pragma unroll
                for (int i = 0; i < 8; ++i) {
                    vf2 hv = hb[i];
                    int ko = kb * 16 + i * 2;
                    #pragma unroll
                    for (int g = 0; g < 6; ++g) {
                        a01[g]     += (*(const vf2*)(wp0[g] + ko)) * hv;
                        a01[6 + g] += (*(const vf2*)(wpi[g] + ko)) * hv;
                    }
                }
            }
            #pragma unroll
            for (int g = 0; g < 12; ++g) pl[(v * 12 + g) * 64 + m] = a01[g].x + a01[g].y;
        }
        __syncthreads();
        // ---- combine A (v0, both columns): h0(s) paired update + gi1 regs ----
        if (v == 0) {
            if (s <= 511) {
                vf2 hr = {0,0}, hz = {0,0}, hn = {0,0};
                #pragma unroll
                for (int u = 0; u < 8; ++u) {
                    hr.x += pl[(u * 12 + 0) * 64 + m]; hr.y += pl[(u * 12 + 1) * 64 + m];
                    hz.x += pl[(u * 12 + 2) * 64 + m]; hz.y += pl[(u * 12 + 3) * 64 + m];
                    hn.x += pl[(u * 12 + 4) * 64 + m]; hn.y += pl[(u * 12 + 5) * 64 + m];
                }
                const float* xp = xT + ((size_t)s * 64 + m) * 16;
                vf2 ir = {0,0}, iz = {0,0}, in_ = {0,0};
                #pragma unroll
                for (int k = 0; k < 16; ++k) {
                    float xv = xp[k];
                    ir.x  += Wih0[(size_t)(c0) * 16 + k] * xv;
                    ir.y  += Wih0[(size_t)(c0 + 1) * 16 + k] * xv;
                    iz.x  += Wih0[(size_t)(512 + c0) * 16 + k] * xv;
                    iz.y  += Wih0[(size_t)(512 + c0 + 1) * 16 + k] * xv;
                    in_.x += Wih0[(size_t)(1024 + c0) * 16 + k] * xv;
                    in_.y += Wih0[(size_t)(1024 + c0 + 1) * 16 + k] * xv;
                }
                vf2 hold = cload2(&h0buf[pr0 * 32768 + w * 128 + m * 2]);
                vf2 hnew;
                #pragma unroll
                for (int j = 0; j < 2; ++j) {
                    float r = 1.f / (1.f + expf(-(ir[j] + hr[j] + br0[j])));
                    float z = 1.f / (1.f + expf(-(iz[j] + hz[j] + bz0[j])));
                    float n = tanhf(in_[j] + bin0[j] + r * (hn[j] + bhn0[j]));
                    hnew[j] = (1.f - z) * n + z * hold[j];
                }
                cstore2(&h0buf[pw0 * 32768 + w * 128 + m * 2], hnew);
            }
            if (s >= 1 && s <= 512) {
                gi_r = bi1r; gi_z = bi1z; gi_n = bi1n;
                #pragma unroll
                for (int u = 0; u < 8; ++u) {
                    gi_r.x += pl[(u * 12 + 6) * 64 + m];  gi_r.y += pl[(u * 12 + 7) * 64 + m];
                    gi_z.x += pl[(u * 12 + 8) * 64 + m];  gi_z.y += pl[(u * 12 + 9) * 64 + m];
                    gi_n.x += pl[(u * 12 + 10) * 64 + m]; gi_n.y += pl[(u * 12 + 11) * 64 + m];
                }
            }
        }
        // ---- arrive-h0(s+1) (tid0) overlapped with wait-h1(s) (wave 1) ----
        __syncthreads();                 // drains h0 cstores for all waves
        if (tid == 0) barf_arrive(flagsA, w, (unsigned)(s + 1));
        if (v == 1) barf_wait(flagsB, m, (unsigned)s);   // s=0 trivially passes
        __syncthreads();
        // ---- biophys (WG0): consume apre(s-1) -> theta(s-3) ----
        if (w == 0 && s >= 3) {
            int mc = tid >> 3, j = tid & 7;
            const float* ap = apre_g + ((s + 1) & 1) * 1024;
            float a0 = 1.f / (1.f + expf(-(cload(&ap[(2 * j) * 64 + mc]) + fb0)));
            float a1 = 1.f / (1.f + expf(-(cload(&ap[(2 * j + 1) * 64 + mc]) + fb1)));
            float F0 = (100.f + 2000.f * a0) * (0.06f + 0.006f * a0 + 0.05f * th);
            float F1 = (100.f + 2000.f * a1) * (0.06f + 0.006f * a1 - 0.05f * th);
            float tau = 0.05f * (F1 - F0);
            float acc = (tau - 5.f * th - 0.3f * om) * 250.f;
            om += (1.f / 60.f) * acc;
            th += (1.f / 60.f) * om;
            out[((size_t)mc * 512 + (s - 3)) * 8 + j] = th;
        }
        // ---- phase 3: Whh1 + FC dots over h1(s-1), packed pairs ----
        if (s >= 1 && s <= 513) {
            vf2 a2[6];
            #pragma unroll
            for (int g = 0; g < 6; ++g) a2[g] = (vf2){0.f, 0.f};
            vf2 fd = {0.f, 0.f};
            #pragma unroll 1
            for (int kb = 0; kb < 4; ++kb) {
                vf2 hb[8];
                const float* hp = h1buf + (s & 1) * 32768 + (ksu / 2 + kb * 8) * 128 + m * 2;
                #pragma unroll
                for (int i = 0; i < 8; ++i) hb[i] = cload2(hp + i * 128);
                #pragma unroll
                for (int i = 0; i < 8; ++i) {
                    vf2 hv = hb[i];
                    int ko = kb * 16 + i * 2;
                    #pragma unroll
                    for (int g = 0; g < 6; ++g)
                        a2[g] += (*(const vf2*)(wp1[g] + ko)) * hv;
                    fd += (*(const vf2*)(fcp + ko)) * hv;
                }
            }
            if (s <= 512) {
                #pragma unroll
                for (int g = 0; g < 6; ++g) pl[(v * 12 + g) * 64 + m] = a2[g].x + a2[g].y;
            }
            if (isFC && s >= 2) pl2[v * 64 + m] = fd.x + fd.y;
        }
        __syncthreads();
        // ---- combine B (v0, both columns): h1(s) paired update ----
        if (s >= 1 && s <= 512 && v == 0) {
            vf2 hr = {0,0}, hz = {0,0}, hn = {0,0};
            #pragma unroll
            for (int u = 0; u < 8; ++u) {
                hr.x += pl[(u * 12 + 0) * 64 + m]; hr.y += pl[(u * 12 + 1) * 64 + m];
                hz.x += pl[(u * 12 + 2) * 64 + m]; hz.y += pl[(u * 12 + 3) * 64 + m];
                hn.x += pl[(u * 12 + 4) * 64 + m]; hn.y += pl[(u * 12 + 5) * 64 + m];
            }
            vf2 hold = cload2(&h1buf[(s & 1) * 32768 + w * 128 + m * 2]);
            vf2 hnew;
            #pragma unroll
            for (int j = 0; j < 2; ++j) {
                float r = 1.f / (1.f + expf(-(gi_r[j] + hr[j] + bh1r[j])));
                float z = 1.f / (1.f + expf(-(gi_z[j] + hz[j] + bh1z[j])));
                float n = tanhf(gi_n[j] + r * (hn[j] + bh1n[j]));
                hnew[j] = (1.f - z) * n + z * hold[j];
            }
            cstore2(&h1buf[((s + 1) & 1) * 32768 + w * 128 + m * 2], hnew);
        }
        if (isFC && s >= 2 && s <= 513 && v == 2) {
            float p = 0.f;
            #pragma unroll
            for (int u = 0; u < 8; ++u) p += pl2[u * 64 + m];
            cstore(&apre_g[(s & 1) * 1024 + (w - 8) * 64 + m], p);
        }
        if (s == 514) break;
        // ---- arrive-h1(s+1): end of step ----
        __syncthreads();                 // drains h1/apre cstores
        if (tid == 0) barf_arrive(flagsB, w, (unsigned)(s + 1));
    }
}

// ---------------------------------------------------------------------------
extern "C" void kernel_launch(void* const* d_in, const int* in_sizes, int n_in,
                              void* d_out, int out_size, void* d_ws, size_t ws_size,
                              hipStream_t stream) {
    const float* x     = (const float*)d_in[0];
    const float* W_ih0 = (const float*)d_in[1];
    const float* W_hh0 = (const float*)d_in[2];
    const float* b_ih0 = (const float*)d_in[3];
    const float* b_hh0 = (const float*)d_in[4];
    const float* W_ih1 = (const float*)d_in[5];
    const float* W_hh1 = (const float*)d_in[6];
    const float* b_ih1 = (const float*)d_in[7];
    const float* b_hh1 = (const float*)d_in[8];
    const float* fc_W  = (const float*)d_in[9];
    const float* fc_b  = (const float*)d_in[10];
    const float* h0    = (const float*)d_in[11];
    const float* th0   = (const float*)d_in[12];
    const float* om0   = (const float*)d_in[13];
    float* out = (float*)d_out;

    float* ws = (float*)d_ws;
    float* h0buf  = ws;                 // 2 x [256 pairs][64 chains][2] parity buffers
    float* h1buf  = h0buf + 65536;
    float* apre_g = h1buf + 65536;      // 2 x [16][64]
    unsigned* bar = (unsigned*)(apre_g + 2048);    // 1024 uints (two flag arrays)
    float* xT     = (float*)(bar + 1024);          // [512][64][16]

    k_init<<<260, 256, 0, stream>>>(h0, h0buf, h1buf, bar);
    k_xt<<<512, 256, 0, stream>>>(x, xT);

    void* args[] = {(void*)&xT, (void*)&W_ih0, (void*)&W_hh0, (void*)&b_ih0,
                    (void*)&b_hh0, (void*)&W_ih1, (void*)&W_hh1, (void*)&b_ih1,
                    (void*)&b_hh1, (void*)&fc_W, (void*)&fc_b,
                    (void*)&th0, (void*)&om0, (void*)&out, (void*)&h0buf,
                    (void*)&h1buf, (void*)&apre_g, (void*)&bar};
    (void)hipLaunchCooperativeKernel((void*)k_fused, dim3(NWG), dim3(NTH),
                                     args, 0, stream);
}